// Round 5
// baseline (9220.428 us; speedup 1.0000x reference)
//
#include <hip/hip_runtime.h>
#include <hip/hip_cooperative_groups.h>

namespace cg = cooperative_groups;

typedef __attribute__((ext_vector_type(8))) short short8;
typedef __attribute__((ext_vector_type(4))) float f32x4;

#define NBATCH 256
#define NSTEP  128
#define NFEAT  128
#define NHID   1024
#define KA     1152
#define KB     2048
#define NOUT   128
#define KOUT   131072
#define NBLK   256

// LDS layout (bytes)
#define W1_OFF 0
#define W1_BYTES (16 * KB * 2)           // 65536
#define W0_OFF (W1_OFF + W1_BYTES)
#define W0_BYTES (16 * KA * 2)           // 36864
#define HS0_OFF (W0_OFF + W0_BYTES)      // 102400
#define HS1_OFF (HS0_OFF + 2048)
#define SMEM_BYTES (HS1_OFF + 2048)      // 106496

__device__ __forceinline__ unsigned short f2bf(float f){
  unsigned u = __float_as_uint(f);
  u += 0x7fffu + ((u >> 16) & 1u);
  return (unsigned short)(u >> 16);
}
__device__ __forceinline__ float sigf(float x){
  x = fminf(fmaxf(x, -30.f), 30.f);
  return 1.f / (1.f + __expf(-x));
}
__device__ __forceinline__ float tanhf_(float x){
  x = fminf(fmaxf(x, -15.f), 15.f);
  float e = __expf(2.f * x);
  return (e - 1.f) / (e + 1.f);
}

struct Params {
  const float *batch,*Wih0,*Whh0,*bih0,*bhh0,*Wih1,*Whh1,*bih1,*bhh1,*h00,*c00,*h01,*c01,*Wout,*bout;
  float *out;
  unsigned short *h0b,*h1b,*outs,*xbf;
  float *partial;
  unsigned *ctr;
};

__device__ __forceinline__ short8 ld8(const unsigned short* p){
  return *(const short8*)p;
}
// agent-coherent 16B load as two relaxed agent-scope 8B atomic loads (bypasses stale L2/L0)
__device__ __forceinline__ short8 ld8a(const unsigned short* p){
  union { unsigned long long q[2]; short8 v; } u;
  unsigned long long* pq = (unsigned long long*)p;
  u.q[0] = __hip_atomic_load(pq,     __ATOMIC_RELAXED, __HIP_MEMORY_SCOPE_AGENT);
  u.q[1] = __hip_atomic_load(pq + 1, __ATOMIC_RELAXED, __HIP_MEMORY_SCOPE_AGENT);
  return u.v;
}
__device__ __forceinline__ short8 ld8f(const float* p){
  f32x4 a = *(const f32x4*)p;
  f32x4 b = *(const f32x4*)(p + 4);
  short8 r;
  r[0]=(short)f2bf(a[0]); r[1]=(short)f2bf(a[1]); r[2]=(short)f2bf(a[2]); r[3]=(short)f2bf(a[3]);
  r[4]=(short)f2bf(b[0]); r[5]=(short)f2bf(b[1]); r[6]=(short)f2bf(b[2]); r[7]=(short)f2bf(b[3]);
  return r;
}

// lightweight grid barrier: one fresh counter per phase (zeroed at setup each launch)
__device__ __forceinline__ void gbar(unsigned* c, int tid){
  __syncthreads();   // drains vmcnt(0): all this block's agent stores are at MALL
  if (tid == 0) {
    asm volatile("" ::: "memory");
    __hip_atomic_fetch_add(c, 1u, __ATOMIC_RELAXED, __HIP_MEMORY_SCOPE_AGENT);
    while (__hip_atomic_load(c, __ATOMIC_RELAXED, __HIP_MEMORY_SCOPE_AGENT) < (unsigned)NBLK)
      __builtin_amdgcn_s_sleep(2);
    asm volatile("" ::: "memory");
  }
  __syncthreads();
}

// ---- software pipeline pieces (all compile-time indexed) ----
__device__ __forceinline__ void ldh(short8 (&buf)[8], const unsigned short* ha,
                                    const unsigned short* hb, int kb){
  #pragma unroll
  for (int q = 0; q < 4; q++) {
    buf[2*q]   = ld8a(ha + kb + q*32);
    buf[2*q+1] = ld8a(hb + kb + q*32);
  }
}
template<int H>
__device__ __forceinline__ void ch0(const short8 (&buf)[8], const char* smem,
                                    int lo, int klane,
                                    f32x4& l0a0, f32x4& l0a1, f32x4& l1a0, f32x4& l1a1){
  #pragma unroll
  for (int q = 0; q < 4; q++) {
    int kk = H*128 + q*32 + klane;
    int offA = ((lo * KA + NFEAT + kk) * 2) ^ ((lo & 7) << 4);
    int offB = ((lo * KB + kk) * 2) ^ ((lo & 7) << 4);
    short8 w0f = *(const short8*)(smem + W0_OFF + offA);
    short8 w1f = *(const short8*)(smem + W1_OFF + offB);
    l0a0 = __builtin_amdgcn_mfma_f32_16x16x32_bf16(w0f, buf[2*q],   l0a0, 0, 0, 0);
    l0a1 = __builtin_amdgcn_mfma_f32_16x16x32_bf16(w0f, buf[2*q+1], l0a1, 0, 0, 0);
    l1a0 = __builtin_amdgcn_mfma_f32_16x16x32_bf16(w1f, buf[2*q],   l1a0, 0, 0, 0);
    l1a1 = __builtin_amdgcn_mfma_f32_16x16x32_bf16(w1f, buf[2*q+1], l1a1, 0, 0, 0);
  }
}
template<int H>
__device__ __forceinline__ void ch1(const short8 (&buf)[8], const char* smem,
                                    int lo, int klane, f32x4& l1a0, f32x4& l1a1){
  #pragma unroll
  for (int q = 0; q < 4; q++) {
    int kk = H*128 + q*32 + klane;
    int off = ((lo * KB + NHID + kk) * 2) ^ ((lo & 7) << 4);
    short8 wf = *(const short8*)(smem + W1_OFF + off);
    l1a0 = __builtin_amdgcn_mfma_f32_16x16x32_bf16(wf, buf[2*q],   l1a0, 0, 0, 0);
    l1a1 = __builtin_amdgcn_mfma_f32_16x16x32_bf16(wf, buf[2*q+1], l1a1, 0, 0, 0);
  }
}

__global__ void __launch_bounds__(512, 2) lstm_all(Params a)
{
  extern __shared__ char smem[];
  const int bx = blockIdx.x, tid = threadIdx.x;
  const int gtid = bx * 512 + tid, nthr = gridDim.x * 512;
  const int w = tid >> 6, l = tid & 63, lo = l & 15, hi = l >> 4;
  const int klane = hi * 8;

  // ---------------- setup ----------------
  for (int i = tid; i < 256; i += 512) if (bx == 0) a.ctr[i] = 0;
  for (int item = tid; item < 16 * 256; item += 512) {
    int lr = item >> 8, k = (item & 255) * 8;
    int r = 16 * bx + lr, orig = (r & 3) * NHID + (r >> 2);
    const float* src = (k < NHID) ? a.Wih1 + (size_t)orig * NHID + k
                                  : a.Whh1 + (size_t)orig * NHID + (k - NHID);
    int off = (lr * KB + k) * 2;
    off ^= (lr & 7) << 4;
    *(short8*)(smem + W1_OFF + off) = ld8f(src);
  }
  for (int item = tid; item < 16 * 144; item += 512) {
    int lr = item / 144, k = (item % 144) * 8;
    int r = 16 * bx + lr, orig = (r & 3) * NHID + (r >> 2);
    const float* src = (k < NFEAT) ? a.Wih0 + (size_t)orig * NFEAT + k
                                   : a.Whh0 + (size_t)orig * NHID + (k - NFEAT);
    int off = (lr * KA + k) * 2;
    off ^= (lr & 7) << 4;
    *(short8*)(smem + W0_OFF + off) = ld8f(src);
  }
  for (int i = gtid; i < NBATCH * NHID; i += nthr) {
    a.h0b[NBATCH * NHID + i] = f2bf(a.h00[i]);
    a.h1b[NBATCH * NHID + i] = f2bf(a.h01[i]);
  }
  for (int i = gtid; i < NSTEP * NBATCH * NFEAT / 8; i += nthr)
    *(short8*)(a.xbf + (size_t)i * 8) = ld8f(a.batch + (size_t)i * 8);

  // per-lane persistent state: unit j = 4*bx + hi, batch rows m = w*32 + {lo, 16+lo}
  const int j = 4 * bx + hi;
  float b0r[4], b1r[4];
  #pragma unroll
  for (int q = 0; q < 4; q++) {
    b0r[q] = a.bih0[q * NHID + j] + a.bhh0[q * NHID + j];
    b1r[q] = a.bih1[q * NHID + j] + a.bhh1[q * NHID + j];
  }
  float c0r[2], c1r[2];
  #pragma unroll
  for (int mf = 0; mf < 2; mf++) {
    int m = w * 32 + mf * 16 + lo;
    c0r[mf] = a.c00[(size_t)m * NHID + j];
    c1r[mf] = a.c01[(size_t)m * NHID + j];
  }
  __syncthreads();
  cg::this_grid().sync();

  unsigned short* hs0 = (unsigned short*)(smem + HS0_OFF);
  unsigned short* hs1 = (unsigned short*)(smem + HS1_OFF);
  const int m0 = w * 32 + lo, m1 = m0 + 16;

  // ---------------- 129 pipelined phases: layer0 step p || layer1 step p-1 ----------------
  for (int p = 0; p <= NSTEP; p++) {
    const int wpar = p & 1, rp = wpar ^ 1;
    const unsigned short* h0prev = a.h0b + (size_t)rp   * NBATCH * NHID;
    const unsigned short* h1prev = a.h1b + (size_t)wpar * NBATCH * NHID;
    const int t0 = (p < NSTEP) ? p : (NSTEP - 1);

    const unsigned short* h0A = h0prev + (size_t)m0 * NHID + klane;
    const unsigned short* h0B = h0prev + (size_t)m1 * NHID + klane;
    const unsigned short* h1A = h1prev + (size_t)m0 * NHID + klane;
    const unsigned short* h1B = h1prev + (size_t)m1 * NHID + klane;

    f32x4 l0a0 = {0.f,0.f,0.f,0.f}, l0a1 = {0.f,0.f,0.f,0.f};
    f32x4 l1a0 = {0.f,0.f,0.f,0.f}, l1a1 = {0.f,0.f,0.f,0.f};

    // x (plain cached; L2-hot since L2 is never invalidated now)
    short8 xb[8];
    {
      const unsigned short* xp = a.xbf + (size_t)t0 * NBATCH * NFEAT;
      #pragma unroll
      for (int kc = 0; kc < 4; kc++) {
        xb[2*kc]   = ld8(xp + (size_t)m0 * NFEAT + kc*32 + klane);
        xb[2*kc+1] = ld8(xp + (size_t)m1 * NFEAT + kc*32 + klane);
      }
    }

    // 3-buffer ring over 16 half-chunks (8 h0 + 8 h1), 2 issued ahead
    short8 r0[8], r1[8], r2[8];
    ldh(r0, h0A, h0B, 0*128);
    ldh(r1, h0A, h0B, 1*128);
    // seg A: x_t (k = 0..127 of layer0)
    #pragma unroll
    for (int kc = 0; kc < 4; kc++) {
      int off = ((lo * KA + kc * 32 + klane) * 2) ^ ((lo & 7) << 4);
      short8 wf = *(const short8*)(smem + W0_OFF + off);
      l0a0 = __builtin_amdgcn_mfma_f32_16x16x32_bf16(wf, xb[2*kc],   l0a0, 0, 0, 0);
      l0a1 = __builtin_amdgcn_mfma_f32_16x16x32_bf16(wf, xb[2*kc+1], l0a1, 0, 0, 0);
    }
    ldh(r2, h0A, h0B, 2*128); ch0<0>(r0, smem, lo, klane, l0a0, l0a1, l1a0, l1a1);
    ldh(r0, h0A, h0B, 3*128); ch0<1>(r1, smem, lo, klane, l0a0, l0a1, l1a0, l1a1);
    ldh(r1, h0A, h0B, 4*128); ch0<2>(r2, smem, lo, klane, l0a0, l0a1, l1a0, l1a1);
    ldh(r2, h0A, h0B, 5*128); ch0<3>(r0, smem, lo, klane, l0a0, l0a1, l1a0, l1a1);
    ldh(r0, h0A, h0B, 6*128); ch0<4>(r1, smem, lo, klane, l0a0, l0a1, l1a0, l1a1);
    ldh(r1, h0A, h0B, 7*128); ch0<5>(r2, smem, lo, klane, l0a0, l0a1, l1a0, l1a1);
    ldh(r2, h1A, h1B, 0*128); ch0<6>(r0, smem, lo, klane, l0a0, l0a1, l1a0, l1a1);
    ldh(r0, h1A, h1B, 1*128); ch0<7>(r1, smem, lo, klane, l0a0, l0a1, l1a0, l1a1);
    ldh(r1, h1A, h1B, 2*128); ch1<0>(r2, smem, lo, klane, l1a0, l1a1);
    ldh(r2, h1A, h1B, 3*128); ch1<1>(r0, smem, lo, klane, l1a0, l1a1);
    ldh(r0, h1A, h1B, 4*128); ch1<2>(r1, smem, lo, klane, l1a0, l1a1);
    ldh(r1, h1A, h1B, 5*128); ch1<3>(r2, smem, lo, klane, l1a0, l1a1);
    ldh(r2, h1A, h1B, 6*128); ch1<4>(r0, smem, lo, klane, l1a0, l1a1);
    ldh(r0, h1A, h1B, 7*128); ch1<5>(r1, smem, lo, klane, l1a0, l1a1);
    ch1<6>(r2, smem, lo, klane, l1a0, l1a1);
    ch1<7>(r0, smem, lo, klane, l1a0, l1a1);

    // epilogues (lane-local cell update; gates i,f,g,o in acc[0..3])
    if (p < NSTEP) {
      float cn0 = sigf(l0a0[1] + b0r[1]) * c0r[0] + sigf(l0a0[0] + b0r[0]) * tanhf_(l0a0[2] + b0r[2]);
      c0r[0] = cn0;
      hs0[(w * 32 + lo) * 4 + hi] = f2bf(sigf(l0a0[3] + b0r[3]) * tanhf_(cn0));
      float cn1 = sigf(l0a1[1] + b0r[1]) * c0r[1] + sigf(l0a1[0] + b0r[0]) * tanhf_(l0a1[2] + b0r[2]);
      c0r[1] = cn1;
      hs0[(w * 32 + 16 + lo) * 4 + hi] = f2bf(sigf(l0a1[3] + b0r[3]) * tanhf_(cn1));
    }
    if (p >= 1) {
      float cn0 = sigf(l1a0[1] + b1r[1]) * c1r[0] + sigf(l1a0[0] + b1r[0]) * tanhf_(l1a0[2] + b1r[2]);
      c1r[0] = cn0;
      hs1[(w * 32 + lo) * 4 + hi] = f2bf(sigf(l1a0[3] + b1r[3]) * tanhf_(cn0));
      float cn1 = sigf(l1a1[1] + b1r[1]) * c1r[1] + sigf(l1a1[0] + b1r[0]) * tanhf_(l1a1[2] + b1r[2]);
      c1r[1] = cn1;
      hs1[(w * 32 + 16 + lo) * 4 + hi] = f2bf(sigf(l1a1[3] + b1r[3]) * tanhf_(cn1));
    }
    __syncthreads();
    if (tid < NBATCH) {
      if (p < NSTEP) {
        unsigned long long v = *(const unsigned long long*)(hs0 + tid * 4);
        __hip_atomic_store((unsigned long long*)(a.h0b + (size_t)wpar * NBATCH * NHID + (size_t)tid * NHID + 4 * bx),
                           v, __ATOMIC_RELAXED, __HIP_MEMORY_SCOPE_AGENT);
      }
      if (p >= 1) {
        unsigned long long v = *(const unsigned long long*)(hs1 + tid * 4);
        __hip_atomic_store((unsigned long long*)(a.h1b + (size_t)rp * NBATCH * NHID + (size_t)tid * NHID + 4 * bx),
                           v, __ATOMIC_RELAXED, __HIP_MEMORY_SCOPE_AGENT);
        *(unsigned long long*)(a.outs + (size_t)(p - 1) * NBATCH * NHID + (size_t)tid * NHID + 4 * bx) = v;
      }
    }
    gbar(a.ctr + p, tid);
  }

  cg::this_grid().sync();   // release outs (wb L2) + acquire for final GEMM

  // ---------------- final GEMM: out[i][o] = outs_flat[i,:] . Wout[o,:] + bout ----------------
  {
    int fnt = bx & 3, kc = bx >> 2;      // 4 o-tiles x 64 k-chunks of 2048
    f32x4 facc[2][2];
    #pragma unroll
    for (int i = 0; i < 2; i++) { facc[i][0] = (f32x4)(0.f); facc[i][1] = (f32x4)(0.f); }
    const int kbase = kc * 2048;
    #pragma unroll 2
    for (int kk = 0; kk < 64; kk++) {
      short8 wf0 = ld8f(a.Wout + (size_t)(fnt * 32 +  0 + lo) * KOUT + kbase + kk * 32 + hi * 8);
      short8 wf1 = ld8f(a.Wout + (size_t)(fnt * 32 + 16 + lo) * KOUT + kbase + kk * 32 + hi * 8);
      #pragma unroll
      for (int mf = 0; mf < 2; mf++) {
        const unsigned short* ip = a.outs + (size_t)((w * 2 + mf) * 16 + lo) * KOUT + kbase + kk * 32 + hi * 8;
        short8 af = ld8(ip);
        facc[mf][0] = __builtin_amdgcn_mfma_f32_16x16x32_bf16(wf0, af, facc[mf][0], 0, 0, 0);
        facc[mf][1] = __builtin_amdgcn_mfma_f32_16x16x32_bf16(wf1, af, facc[mf][1], 0, 0, 0);
      }
    }
    #pragma unroll
    for (int mf = 0; mf < 2; mf++)
      #pragma unroll
      for (int nf = 0; nf < 2; nf++)
        #pragma unroll
        for (int r = 0; r < 4; r++) {
          int o_loc = nf * 16 + 4 * hi + r;
          int i = (w * 2 + mf) * 16 + lo;
          a.partial[(size_t)(kc * 4 + fnt) * 8192 + o_loc * 256 + i] = facc[mf][nf][r];
        }
  }
  cg::this_grid().sync();

  for (int idx = gtid; idx < NBATCH * NOUT; idx += nthr) {
    int i = idx >> 7, o = idx & 127;
    float s = a.bout[o];
    #pragma unroll 4
    for (int kc2 = 0; kc2 < 64; kc2++)
      s += a.partial[(size_t)(kc2 * 4 + (o >> 5)) * 8192 + (o & 31) * 256 + i];
    a.out[idx] = s;
  }
}

extern "C" void kernel_launch(void* const* d_in, const int* in_sizes, int n_in,
                              void* d_out, int out_size, void* d_ws, size_t ws_size,
                              hipStream_t stream)
{
  (void)in_sizes; (void)n_in; (void)out_size; (void)ws_size;
  Params a;
  a.batch = (const float*)d_in[0];  a.Wih0 = (const float*)d_in[1];
  a.Whh0  = (const float*)d_in[2];  a.bih0 = (const float*)d_in[3];
  a.bhh0  = (const float*)d_in[4];  a.Wih1 = (const float*)d_in[5];
  a.Whh1  = (const float*)d_in[6];  a.bih1 = (const float*)d_in[7];
  a.bhh1  = (const float*)d_in[8];  a.h00  = (const float*)d_in[9];
  a.c00   = (const float*)d_in[10]; a.h01  = (const float*)d_in[11];
  a.c01   = (const float*)d_in[12]; a.Wout = (const float*)d_in[13];
  a.bout  = (const float*)d_in[14];
  a.out   = (float*)d_out;

  char* ws = (char*)d_ws;
  size_t off = 0;
  auto carve = [&](size_t bytes) { char* p = ws + off; off += (bytes + 255) & ~(size_t)255; return p; };
  a.h0b     = (unsigned short*)carve((size_t)2 * NBATCH * NHID * 2);
  a.h1b     = (unsigned short*)carve((size_t)2 * NBATCH * NHID * 2);
  a.outs    = (unsigned short*)carve((size_t)NSTEP * NBATCH * NHID * 2);
  a.xbf     = (unsigned short*)carve((size_t)NSTEP * NBATCH * NFEAT * 2);
  a.partial = (float*)carve((size_t)256 * 8192 * 4);
  a.ctr     = (unsigned*)carve((size_t)256 * 4);

  hipFuncSetAttribute((const void*)lstm_all, hipFuncAttributeMaxDynamicSharedMemorySize, SMEM_BYTES);

  void* kargs[] = { &a };
  hipLaunchCooperativeKernel((void*)lstm_all, dim3(256), dim3(512), kargs, SMEM_BYTES, stream);
}

// Round 6
// 6890.375 us; speedup vs baseline: 1.3382x; 1.3382x over previous
//
#include <hip/hip_runtime.h>
#include <hip/hip_cooperative_groups.h>

namespace cg = cooperative_groups;

typedef __attribute__((ext_vector_type(8))) short short8;
typedef __attribute__((ext_vector_type(4))) float f32x4;

#define NBATCH 256
#define NSTEP  128
#define NFEAT  128
#define NHID   1024
#define NOUT   128
#define KOUT   131072

// LDS layout (bytes): W0h [16][1024] (32KB) | W1 [16][2048] (64KB) | chunk0 32KB | chunk1 32KB
#define W0H_OFF 0
#define W1_OFF  32768
#define CH0_OFF 98304
#define CH1_OFF 131072
#define SMEM_BYTES 163840

#define MFMA __builtin_amdgcn_mfma_f32_16x16x32_bf16

__device__ __forceinline__ unsigned short f2bf(float f){
  unsigned u = __float_as_uint(f);
  u += 0x7fffu + ((u >> 16) & 1u);
  return (unsigned short)(u >> 16);
}
__device__ __forceinline__ float sigf(float x){
  x = fminf(fmaxf(x, -30.f), 30.f);
  return 1.f / (1.f + __expf(-x));
}
__device__ __forceinline__ float tanhf_(float x){
  x = fminf(fmaxf(x, -15.f), 15.f);
  float e = __expf(2.f * x);
  return (e - 1.f) / (e + 1.f);
}

struct Params {
  const float *batch,*Wih0,*Whh0,*bih0,*bhh0,*Wih1,*Whh1,*bih1,*bhh1,*h00,*c00,*h01,*c01,*Wout,*bout;
  float *out;
  unsigned short *h0b,*h1b,*outs,*xbf;
  float *partial;
};

__device__ __forceinline__ short8 ld8(const unsigned short* p){
  return *(const short8*)p;
}
__device__ __forceinline__ short8 ld8f(const float* p){
  f32x4 a = *(const f32x4*)p;
  f32x4 b = *(const f32x4*)(p + 4);
  short8 r;
  r[0]=(short)f2bf(a[0]); r[1]=(short)f2bf(a[1]); r[2]=(short)f2bf(a[2]); r[3]=(short)f2bf(a[3]);
  r[4]=(short)f2bf(b[0]); r[5]=(short)f2bf(b[1]); r[6]=(short)f2bf(b[2]); r[7]=(short)f2bf(b[3]);
  return r;
}

// async global->LDS, 16B per lane, dest = wave-uniform base + lane*16
__device__ __forceinline__ void dma16(const void* g, void* l){
  __builtin_amdgcn_global_load_lds((const __attribute__((address_space(1))) unsigned int*)g,
                                   (__attribute__((address_space(3))) unsigned int*)l, 16, 0, 0);
}

// Stage one [256 m][64 k] bf16 chunk (32KB) into LDS buffer `buf`.
// LDS layout: row m = 128B; granule position u' holds global granule (u' ^ (m&7)).
__device__ __forceinline__ void dma_chunk(char* smem, int buf, int tid,
                                          const unsigned short* src, int rowStride, int kOff){
  char* base = smem + (buf ? CH1_OFF : CH0_OFF) + (tid >> 6) * 1024;
  #pragma unroll
  for (int i = 0; i < 4; i++) {
    int m  = i * 64 + (tid >> 3);
    int ul = (tid & 7) ^ (m & 7);
    dma16(src + (size_t)m * rowStride + kOff + ul * 8, base + i * 8192);
  }
}

// read act frag: rows mr, k-granule (s*4+hi) of the chunk (swizzle-corrected)
__device__ __forceinline__ short8 rda(const char* smem, int buf, int mr, int s, int hi){
  int g = ((s << 2) + hi) ^ (mr & 7);
  return *(const short8*)(smem + (buf ? CH1_OFF : CH0_OFF) + mr * 128 + g * 16);
}

__global__ void __launch_bounds__(512, 2) lstm_all(Params a)
{
  extern __shared__ char smem[];
  const int bx = blockIdx.x, tid = threadIdx.x;
  const int gtid = bx * 512 + tid, nthr = gridDim.x * 512;
  const int w = tid >> 6, l = tid & 63, lo = l & 15, hi = l >> 4;
  const int klane = hi * 8;
  const int swz = (lo & 7) << 4;

  // ---------------- setup ----------------
  // W0 h-segment (Whh0) -> LDS [16][1024]
  for (int item = tid; item < 16 * 128; item += 512) {
    int lr = item >> 7, kx = (item & 127) * 8;
    int r = 16 * bx + lr, orig = (r & 3) * NHID + (r >> 2);
    int off = ((lr * 1024 + kx) * 2) ^ ((lr & 7) << 4);
    *(short8*)(smem + W0H_OFF + off) = ld8f(a.Whh0 + (size_t)orig * NHID + kx);
  }
  // W1 -> LDS [16][2048]
  for (int item = tid; item < 16 * 256; item += 512) {
    int lr = item >> 8, k = (item & 255) * 8;
    int r = 16 * bx + lr, orig = (r & 3) * NHID + (r >> 2);
    const float* src = (k < NHID) ? a.Wih1 + (size_t)orig * NHID + k
                                  : a.Whh1 + (size_t)orig * NHID + (k - NHID);
    int off = ((lr * 2048 + k) * 2) ^ ((lr & 7) << 4);
    *(short8*)(smem + W1_OFF + off) = ld8f(src);
  }
  // W0 x-segment (Wih0) -> registers (per wave, 4 frags)
  short8 wx0, wx1, wx2, wx3;
  {
    int r = 16 * bx + lo, orig = (r & 3) * NHID + (r >> 2);
    const float* s = a.Wih0 + (size_t)orig * NFEAT;
    wx0 = ld8f(s + 0 * 32 + klane); wx1 = ld8f(s + 1 * 32 + klane);
    wx2 = ld8f(s + 2 * 32 + klane); wx3 = ld8f(s + 3 * 32 + klane);
  }
  // h-state init into buffer 1; x pre-cast to bf16.
  for (int i = gtid; i < NBATCH * NHID; i += nthr) {
    a.h0b[NBATCH * NHID + i] = f2bf(a.h00[i]);
    a.h1b[NBATCH * NHID + i] = f2bf(a.h01[i]);
  }
  for (int i = gtid; i < NSTEP * NBATCH * NFEAT / 8; i += nthr)
    *(short8*)(a.xbf + (size_t)i * 8) = ld8f(a.batch + (size_t)i * 8);

  // per-lane persistent state: unit j = 4*bx + hi, batch rows m = w*32 + {lo, 16+lo}
  const int j = 4 * bx + hi;
  float b0r[4], b1r[4];
  #pragma unroll
  for (int q = 0; q < 4; q++) {
    b0r[q] = a.bih0[q * NHID + j] + a.bhh0[q * NHID + j];
    b1r[q] = a.bih1[q * NHID + j] + a.bhh1[q * NHID + j];
  }
  const int m0 = w * 32 + lo, m1 = m0 + 16;
  float c0r[2], c1r[2];
  c0r[0] = a.c00[(size_t)m0 * NHID + j]; c0r[1] = a.c00[(size_t)m1 * NHID + j];
  c1r[0] = a.c01[(size_t)m0 * NHID + j]; c1r[1] = a.c01[(size_t)m1 * NHID + j];
  __syncthreads();
  cg::this_grid().sync();

  // ---------------- 129 pipelined phases: layer0 step p || layer1 step p-1 ----------------
  // 34 chunks/phase: 0-1 = x (k 0..127), 2-17 = h0 (k 0..1023), 18-33 = h1 (k 0..1023)
  // protocol per chunk: __syncthreads (drains own DMA, joins block) ; issue next ; consume cur
  for (int p = 0; p <= NSTEP; p++) {
    const int wpar = p & 1, rp = wpar ^ 1;
    const unsigned short* h0p = a.h0b + (size_t)rp   * NBATCH * NHID;
    const unsigned short* h1p = a.h1b + (size_t)wpar * NBATCH * NHID;
    const int t0 = (p < NSTEP) ? p : (NSTEP - 1);
    const unsigned short* xp = a.xbf + (size_t)t0 * NBATCH * NFEAT;

    f32x4 l0a0 = {0.f,0.f,0.f,0.f}, l0a1 = {0.f,0.f,0.f,0.f};
    f32x4 l1a0 = {0.f,0.f,0.f,0.f}, l1a1 = {0.f,0.f,0.f,0.f};

    dma_chunk(smem, 0, tid, xp, NFEAT, 0);                  // chunk 0

    // c = 0 (x, buf0, W from regs wx0/wx1)
    __syncthreads();
    dma_chunk(smem, 1, tid, xp, NFEAT, 64);                 // chunk 1
    {
      short8 a0 = rda(smem, 0, m0, 0, hi), a1 = rda(smem, 0, m1, 0, hi);
      l0a0 = MFMA(wx0, a0, l0a0, 0,0,0); l0a1 = MFMA(wx0, a1, l0a1, 0,0,0);
      a0 = rda(smem, 0, m0, 1, hi); a1 = rda(smem, 0, m1, 1, hi);
      l0a0 = MFMA(wx1, a0, l0a0, 0,0,0); l0a1 = MFMA(wx1, a1, l0a1, 0,0,0);
    }
    // c = 1 (x, buf1, wx2/wx3)
    __syncthreads();
    dma_chunk(smem, 0, tid, h0p, NHID, 0);                  // chunk 2
    {
      short8 a0 = rda(smem, 1, m0, 0, hi), a1 = rda(smem, 1, m1, 0, hi);
      l0a0 = MFMA(wx2, a0, l0a0, 0,0,0); l0a1 = MFMA(wx2, a1, l0a1, 0,0,0);
      a0 = rda(smem, 1, m0, 1, hi); a1 = rda(smem, 1, m1, 1, hi);
      l0a0 = MFMA(wx3, a0, l0a0, 0,0,0); l0a1 = MFMA(wx3, a1, l0a1, 0,0,0);
    }
    // c = 2..17: h0 chunks feed BOTH layers
    for (int c = 2; c < 18; ++c) {
      __syncthreads();
      if (c < 17) dma_chunk(smem, (c + 1) & 1, tid, h0p, NHID, (c - 1) * 64);
      else        dma_chunk(smem, (c + 1) & 1, tid, h1p, NHID, 0);
      const int k0 = (c - 2) * 64, buf = c & 1;
      #pragma unroll
      for (int s = 0; s < 2; s++) {
        int kk = k0 + s * 32 + klane;
        short8 a0 = rda(smem, buf, m0, s, hi);
        short8 a1 = rda(smem, buf, m1, s, hi);
        short8 w0f = *(const short8*)(smem + W0H_OFF + (((lo * 1024 + kk) * 2) ^ swz));
        short8 w1f = *(const short8*)(smem + W1_OFF  + (((lo * 2048 + kk) * 2) ^ swz));
        l0a0 = MFMA(w0f, a0, l0a0, 0,0,0); l0a1 = MFMA(w0f, a1, l0a1, 0,0,0);
        l1a0 = MFMA(w1f, a0, l1a0, 0,0,0); l1a1 = MFMA(w1f, a1, l1a1, 0,0,0);
      }
    }
    // c = 18..33: h1 chunks (layer1 only)
    for (int c = 18; c < 34; ++c) {
      __syncthreads();
      if (c < 33) dma_chunk(smem, (c + 1) & 1, tid, h1p, NHID, (c - 17) * 64);
      const int k0 = (c - 18) * 64, buf = c & 1;
      #pragma unroll
      for (int s = 0; s < 2; s++) {
        int kk = k0 + s * 32 + klane;
        short8 a0 = rda(smem, buf, m0, s, hi);
        short8 a1 = rda(smem, buf, m1, s, hi);
        short8 wf = *(const short8*)(smem + W1_OFF + (((lo * 2048 + 1024 + kk) * 2) ^ swz));
        l1a0 = MFMA(wf, a0, l1a0, 0,0,0); l1a1 = MFMA(wf, a1, l1a1, 0,0,0);
      }
    }

    // epilogues: lane-local cell update (gates i,f,g,o in acc[0..3]); direct 2B stores
    if (p < NSTEP) {
      unsigned short* ho = a.h0b + (size_t)wpar * NBATCH * NHID;
      float cn0 = sigf(l0a0[1] + b0r[1]) * c0r[0] + sigf(l0a0[0] + b0r[0]) * tanhf_(l0a0[2] + b0r[2]);
      c0r[0] = cn0;
      ho[(size_t)m0 * NHID + j] = f2bf(sigf(l0a0[3] + b0r[3]) * tanhf_(cn0));
      float cn1 = sigf(l0a1[1] + b0r[1]) * c0r[1] + sigf(l0a1[0] + b0r[0]) * tanhf_(l0a1[2] + b0r[2]);
      c0r[1] = cn1;
      ho[(size_t)m1 * NHID + j] = f2bf(sigf(l0a1[3] + b0r[3]) * tanhf_(cn1));
    }
    if (p >= 1) {
      unsigned short* h1o = a.h1b + (size_t)rp * NBATCH * NHID;
      unsigned short* oo  = a.outs + (size_t)(p - 1) * NBATCH * NHID;
      float cn0 = sigf(l1a0[1] + b1r[1]) * c1r[0] + sigf(l1a0[0] + b1r[0]) * tanhf_(l1a0[2] + b1r[2]);
      c1r[0] = cn0;
      unsigned short u0 = f2bf(sigf(l1a0[3] + b1r[3]) * tanhf_(cn0));
      h1o[(size_t)m0 * NHID + j] = u0; oo[(size_t)m0 * NHID + j] = u0;
      float cn1 = sigf(l1a1[1] + b1r[1]) * c1r[1] + sigf(l1a1[0] + b1r[0]) * tanhf_(l1a1[2] + b1r[2]);
      c1r[1] = cn1;
      unsigned short u1 = f2bf(sigf(l1a1[3] + b1r[3]) * tanhf_(cn1));
      h1o[(size_t)m1 * NHID + j] = u1; oo[(size_t)m1 * NHID + j] = u1;
    }
    cg::this_grid().sync();
  }

  // ---------------- final GEMM: out[i][o] = outs_flat[i,:] . Wout[o,:] + bout ----------------
  {
    int fnt = bx & 3, kc = bx >> 2;      // 4 o-tiles x 64 k-chunks of 2048
    f32x4 facc[2][2];
    #pragma unroll
    for (int i = 0; i < 2; i++) { facc[i][0] = (f32x4)(0.f); facc[i][1] = (f32x4)(0.f); }
    const int kbase = kc * 2048;
    #pragma unroll 2
    for (int kk = 0; kk < 64; kk++) {
      short8 wf0 = ld8f(a.Wout + (size_t)(fnt * 32 +  0 + lo) * KOUT + kbase + kk * 32 + klane);
      short8 wf1 = ld8f(a.Wout + (size_t)(fnt * 32 + 16 + lo) * KOUT + kbase + kk * 32 + klane);
      #pragma unroll
      for (int mf = 0; mf < 2; mf++) {
        const unsigned short* ip = a.outs + (size_t)((w * 2 + mf) * 16 + lo) * KOUT + kbase + kk * 32 + klane;
        short8 af = ld8(ip);
        facc[mf][0] = MFMA(wf0, af, facc[mf][0], 0,0,0);
        facc[mf][1] = MFMA(wf1, af, facc[mf][1], 0,0,0);
      }
    }
    #pragma unroll
    for (int mf = 0; mf < 2; mf++)
      #pragma unroll
      for (int nf = 0; nf < 2; nf++)
        #pragma unroll
        for (int r = 0; r < 4; r++) {
          int o_loc = nf * 16 + 4 * hi + r;
          int i = (w * 2 + mf) * 16 + lo;
          a.partial[(size_t)(kc * 4 + fnt) * 8192 + o_loc * 256 + i] = facc[mf][nf][r];
        }
  }
  cg::this_grid().sync();

  for (int idx = gtid; idx < NBATCH * NOUT; idx += nthr) {
    int i = idx >> 7, o = idx & 127;
    float s = a.bout[o];
    #pragma unroll 4
    for (int kc2 = 0; kc2 < 64; kc2++)
      s += a.partial[(size_t)(kc2 * 4 + (o >> 5)) * 8192 + (o & 31) * 256 + i];
    a.out[idx] = s;
  }
}

extern "C" void kernel_launch(void* const* d_in, const int* in_sizes, int n_in,
                              void* d_out, int out_size, void* d_ws, size_t ws_size,
                              hipStream_t stream)
{
  (void)in_sizes; (void)n_in; (void)out_size; (void)ws_size;
  Params a;
  a.batch = (const float*)d_in[0];  a.Wih0 = (const float*)d_in[1];
  a.Whh0  = (const float*)d_in[2];  a.bih0 = (const float*)d_in[3];
  a.bhh0  = (const float*)d_in[4];  a.Wih1 = (const float*)d_in[5];
  a.Whh1  = (const float*)d_in[6];  a.bih1 = (const float*)d_in[7];
  a.bhh1  = (const float*)d_in[8];  a.h00  = (const float*)d_in[9];
  a.c00   = (const float*)d_in[10]; a.h01  = (const float*)d_in[11];
  a.c01   = (const float*)d_in[12]; a.Wout = (const float*)d_in[13];
  a.bout  = (const float*)d_in[14];
  a.out   = (float*)d_out;

  char* ws = (char*)d_ws;
  size_t off = 0;
  auto carve = [&](size_t bytes) { char* p = ws + off; off += (bytes + 255) & ~(size_t)255; return p; };
  a.h0b     = (unsigned short*)carve((size_t)2 * NBATCH * NHID * 2);
  a.h1b     = (unsigned short*)carve((size_t)2 * NBATCH * NHID * 2);
  a.outs    = (unsigned short*)carve((size_t)NSTEP * NBATCH * NHID * 2);
  a.xbf     = (unsigned short*)carve((size_t)NSTEP * NBATCH * NFEAT * 2);
  a.partial = (float*)carve((size_t)256 * 8192 * 4);

  hipFuncSetAttribute((const void*)lstm_all, hipFuncAttributeMaxDynamicSharedMemorySize, SMEM_BYTES);

  void* kargs[] = { &a };
  hipLaunchCooperativeKernel((void*)lstm_all, dim3(256), dim3(512), kargs, SMEM_BYTES, stream);
}

// Round 7
// 5570.852 us; speedup vs baseline: 1.6551x; 1.2369x over previous
//
#include <hip/hip_runtime.h>
#include <hip/hip_cooperative_groups.h>

namespace cg = cooperative_groups;

typedef __attribute__((ext_vector_type(8))) short short8;
typedef __attribute__((ext_vector_type(4))) float f32x4;

#define NBATCH 256
#define NSTEP  128
#define NFEAT  128
#define NHID   1024
#define NOUT   128
#define KOUT   131072
#define NBLK   256

// LDS layout (bytes): W0h [16][1024] 32KB | W1 [16][2048] 64KB | 4 chunk buffers 16KB each
#define W0H_OFF 0
#define W1_OFF  32768
#define CH_OFF  98304
#define SMEM_BYTES 163840

#define MFMA __builtin_amdgcn_mfma_f32_16x16x32_bf16

__device__ __forceinline__ unsigned short f2bf(float f){
  unsigned u = __float_as_uint(f);
  u += 0x7fffu + ((u >> 16) & 1u);
  return (unsigned short)(u >> 16);
}
__device__ __forceinline__ float sigf(float x){
  x = fminf(fmaxf(x, -30.f), 30.f);
  return 1.f / (1.f + __expf(-x));
}
__device__ __forceinline__ float tanhf_(float x){
  x = fminf(fmaxf(x, -15.f), 15.f);
  float e = __expf(2.f * x);
  return (e - 1.f) / (e + 1.f);
}

struct Params {
  const float *batch,*Wih0,*Whh0,*bih0,*bhh0,*Wih1,*Whh1,*bih1,*bhh1,*h00,*c00,*h01,*c01,*Wout,*bout;
  float *out;
  unsigned short *h0b,*h1b,*outs,*xbf;
  float *partial;
  unsigned *ctr;
};

__device__ __forceinline__ short8 ld8(const unsigned short* p){
  return *(const short8*)p;
}
__device__ __forceinline__ short8 ld8f(const float* p){
  f32x4 a = *(const f32x4*)p;
  f32x4 b = *(const f32x4*)(p + 4);
  short8 r;
  r[0]=(short)f2bf(a[0]); r[1]=(short)f2bf(a[1]); r[2]=(short)f2bf(a[2]); r[3]=(short)f2bf(a[3]);
  r[4]=(short)f2bf(b[0]); r[5]=(short)f2bf(b[1]); r[6]=(short)f2bf(b[2]); r[7]=(short)f2bf(b[3]);
  return r;
}

// async global->LDS, 16B/lane, dest = wave-uniform base + lane*16
__device__ __forceinline__ void dma16(const void* g, void* l){
  __builtin_amdgcn_global_load_lds((const __attribute__((address_space(1))) unsigned int*)g,
                                   (__attribute__((address_space(3))) unsigned int*)l, 16, 0, 0);
}

// slim grid barrier with explicit agent-scope (device) coherence
__device__ __forceinline__ void slim_bar(unsigned* c, int tid){
  __syncthreads();                 // compiler drains vmcnt(0): stores are in L2
  if (tid == 0) {
    __builtin_amdgcn_fence(__ATOMIC_RELEASE, "agent");   // L2 writeback to MALL
    __hip_atomic_fetch_add(c, 1u, __ATOMIC_RELAXED, __HIP_MEMORY_SCOPE_AGENT);
    while (__hip_atomic_load(c, __ATOMIC_RELAXED, __HIP_MEMORY_SCOPE_AGENT) < (unsigned)NBLK)
      __builtin_amdgcn_s_sleep(2);
  }
  __syncthreads();
  __builtin_amdgcn_fence(__ATOMIC_ACQUIRE, "agent");     // L2 invalidate (per-wave)
}

#define WB4 asm volatile("s_waitcnt vmcnt(4)\n\ts_barrier" ::: "memory")
#define WB2 asm volatile("s_waitcnt vmcnt(2)\n\ts_barrier" ::: "memory")
#define WB0 asm volatile("s_waitcnt vmcnt(0)\n\ts_barrier" ::: "memory")

__global__ void __launch_bounds__(512, 2) lstm_all(Params a)
{
  extern __shared__ char smem[];
  const int bx = blockIdx.x, tid = threadIdx.x;
  const int gtid = bx * 512 + tid, nthr = gridDim.x * 512;
  const int w = tid >> 6, l = tid & 63, lo = l & 15, hi = l >> 4;
  const int klane = hi * 8;
  const int swz = (lo & 7) << 4;
  // DMA source lane mapping: row r0 = w*32 + (l>>2), granule u = l&3
  const int r0 = w * 32 + (l >> 2), u8 = (l & 3) * 8;

  // ---------------- setup ----------------
  if (bx == 0) for (int i = tid; i < 192; i += 512) a.ctr[i] = 0;
  // W0 h-segment (Whh0) -> LDS [16][1024]
  for (int item = tid; item < 16 * 128; item += 512) {
    int lr = item >> 7, kx = (item & 127) * 8;
    int r = 16 * bx + lr, orig = (r & 3) * NHID + (r >> 2);
    int off = ((lr * 1024 + kx) * 2) ^ ((lr & 7) << 4);
    *(short8*)(smem + W0H_OFF + off) = ld8f(a.Whh0 + (size_t)orig * NHID + kx);
  }
  // W1 -> LDS [16][2048]
  for (int item = tid; item < 16 * 256; item += 512) {
    int lr = item >> 8, k = (item & 255) * 8;
    int r = 16 * bx + lr, orig = (r & 3) * NHID + (r >> 2);
    const float* src = (k < NHID) ? a.Wih1 + (size_t)orig * NHID + k
                                  : a.Whh1 + (size_t)orig * NHID + (k - NHID);
    int off = ((lr * 2048 + k) * 2) ^ ((lr & 7) << 4);
    *(short8*)(smem + W1_OFF + off) = ld8f(src);
  }
  // W0 x-segment -> registers
  short8 wx0, wx1, wx2, wx3;
  {
    int r = 16 * bx + lo, orig = (r & 3) * NHID + (r >> 2);
    const float* s = a.Wih0 + (size_t)orig * NFEAT;
    wx0 = ld8f(s + 0 * 32 + klane); wx1 = ld8f(s + 1 * 32 + klane);
    wx2 = ld8f(s + 2 * 32 + klane); wx3 = ld8f(s + 3 * 32 + klane);
  }
  for (int i = gtid; i < NBATCH * NHID; i += nthr) {
    a.h0b[NBATCH * NHID + i] = f2bf(a.h00[i]);
    a.h1b[NBATCH * NHID + i] = f2bf(a.h01[i]);
  }
  for (int i = gtid; i < NSTEP * NBATCH * NFEAT / 8; i += nthr)
    *(short8*)(a.xbf + (size_t)i * 8) = ld8f(a.batch + (size_t)i * 8);

  const int j = 4 * bx + hi;
  float b0r[4], b1r[4];
  #pragma unroll
  for (int q = 0; q < 4; q++) {
    b0r[q] = a.bih0[q * NHID + j] + a.bhh0[q * NHID + j];
    b1r[q] = a.bih1[q * NHID + j] + a.bhh1[q * NHID + j];
  }
  const int m0 = w * 32 + lo, m1 = m0 + 16;
  float c0r[2], c1r[2];
  c0r[0] = a.c00[(size_t)m0 * NHID + j]; c0r[1] = a.c00[(size_t)m1 * NHID + j];
  c1r[0] = a.c01[(size_t)m0 * NHID + j]; c1r[1] = a.c01[(size_t)m1 * NHID + j];
  __syncthreads();
  cg::this_grid().sync();

  // ---------------- 129 pipelined phases ----------------
  // 68 chunks/phase of [256 m][32 k] (16KB): 0-3 x, 4-35 h0, 36-67 h1.
  // 4 LDS buffers, 3 chunks (6 DMA instrs/wave) in flight; raw barrier + counted vmcnt.
  char* chbase = smem + CH_OFF + w * 2048;  // wave's 32-row region inside a buffer
  for (int p = 0; p <= NSTEP; p++) {
    const int wpar = p & 1, rp = wpar ^ 1;
    const unsigned short* h0p = a.h0b + (size_t)rp   * NBATCH * NHID;
    const unsigned short* h1p = a.h1b + (size_t)wpar * NBATCH * NHID;
    const int t0 = (p < NSTEP) ? p : (NSTEP - 1);
    const unsigned short* xA  = a.xbf + (size_t)t0 * NBATCH * NFEAT + (size_t)r0 * NFEAT + u8;
    const unsigned short* h0A = h0p + (size_t)r0 * NHID + u8;
    const unsigned short* h1A = h1p + (size_t)r0 * NHID + u8;

    auto issue = [&](int cc){
      char* base = smem + CH_OFF + (cc & 3) * 16384 + w * 2048;
      if (cc < 4) {
        int ko = cc * 32;
        dma16(xA + ko, base); dma16(xA + 16 * NFEAT + ko, base + 1024);
      } else if (cc < 36) {
        int ko = (cc - 4) * 32;
        dma16(h0A + ko, base); dma16(h0A + 16 * NHID + ko, base + 1024);
      } else {
        int ko = (cc - 36) * 32;
        dma16(h1A + ko, base); dma16(h1A + 16 * NHID + ko, base + 1024);
      }
    };

    f32x4 l0a0 = {0.f,0.f,0.f,0.f}, l0a1 = {0.f,0.f,0.f,0.f};
    f32x4 l1a0 = {0.f,0.f,0.f,0.f}, l1a1 = {0.f,0.f,0.f,0.f};

    issue(0); issue(1); issue(2);

    // ---- x chunks 0..3 (weights in regs) ----
    {
      WB4; issue(3);
      const char* cb = chbase + 0 * 16384;
      short8 a0 = *(const short8*)(cb + lo * 64 + hi * 16);
      short8 a1 = *(const short8*)(cb + 1024 + lo * 64 + hi * 16);
      l0a0 = MFMA(wx0, a0, l0a0, 0,0,0); l0a1 = MFMA(wx0, a1, l0a1, 0,0,0);
    }
    {
      WB4; issue(4);
      const char* cb = chbase + 1 * 16384;
      short8 a0 = *(const short8*)(cb + lo * 64 + hi * 16);
      short8 a1 = *(const short8*)(cb + 1024 + lo * 64 + hi * 16);
      l0a0 = MFMA(wx1, a0, l0a0, 0,0,0); l0a1 = MFMA(wx1, a1, l0a1, 0,0,0);
    }
    {
      WB4; issue(5);
      const char* cb = chbase + 2 * 16384;
      short8 a0 = *(const short8*)(cb + lo * 64 + hi * 16);
      short8 a1 = *(const short8*)(cb + 1024 + lo * 64 + hi * 16);
      l0a0 = MFMA(wx2, a0, l0a0, 0,0,0); l0a1 = MFMA(wx2, a1, l0a1, 0,0,0);
    }
    {
      WB4; issue(6);
      const char* cb = chbase + 3 * 16384;
      short8 a0 = *(const short8*)(cb + lo * 64 + hi * 16);
      short8 a1 = *(const short8*)(cb + 1024 + lo * 64 + hi * 16);
      l0a0 = MFMA(wx3, a0, l0a0, 0,0,0); l0a1 = MFMA(wx3, a1, l0a1, 0,0,0);
    }
    // ---- h0 chunks 4..35: feed BOTH layers ----
    #pragma unroll 4
    for (int c = 4; c < 36; ++c) {
      WB4; issue(c + 3);
      const char* cb = chbase + (c & 3) * 16384;
      short8 a0 = *(const short8*)(cb + lo * 64 + hi * 16);
      short8 a1 = *(const short8*)(cb + 1024 + lo * 64 + hi * 16);
      int kh = (c - 4) * 32 + klane;
      short8 w0f = *(const short8*)(smem + W0H_OFF + (((lo * 1024 + kh) * 2) ^ swz));
      short8 w1f = *(const short8*)(smem + W1_OFF  + (((lo * 2048 + kh) * 2) ^ swz));
      l0a0 = MFMA(w0f, a0, l0a0, 0,0,0); l0a1 = MFMA(w0f, a1, l0a1, 0,0,0);
      l1a0 = MFMA(w1f, a0, l1a0, 0,0,0); l1a1 = MFMA(w1f, a1, l1a1, 0,0,0);
    }
    // ---- h1 chunks 36..64 uniform ----
    #pragma unroll 4
    for (int c = 36; c < 65; ++c) {
      WB4; issue(c + 3);
      const char* cb = chbase + (c & 3) * 16384;
      short8 a0 = *(const short8*)(cb + lo * 64 + hi * 16);
      short8 a1 = *(const short8*)(cb + 1024 + lo * 64 + hi * 16);
      int kh = (c - 36) * 32 + klane;
      short8 wf = *(const short8*)(smem + W1_OFF + (((lo * 2048 + 1024 + kh) * 2) ^ swz));
      l1a0 = MFMA(wf, a0, l1a0, 0,0,0); l1a1 = MFMA(wf, a1, l1a1, 0,0,0);
    }
    // ---- tail: 65 (wait4), 66 (wait2), 67 (wait0) ----
    {
      WB4;
      const char* cb = chbase + (65 & 3) * 16384;
      short8 a0 = *(const short8*)(cb + lo * 64 + hi * 16);
      short8 a1 = *(const short8*)(cb + 1024 + lo * 64 + hi * 16);
      int kh = 29 * 32 + klane;
      short8 wf = *(const short8*)(smem + W1_OFF + (((lo * 2048 + 1024 + kh) * 2) ^ swz));
      l1a0 = MFMA(wf, a0, l1a0, 0,0,0); l1a1 = MFMA(wf, a1, l1a1, 0,0,0);
    }
    {
      WB2;
      const char* cb = chbase + (66 & 3) * 16384;
      short8 a0 = *(const short8*)(cb + lo * 64 + hi * 16);
      short8 a1 = *(const short8*)(cb + 1024 + lo * 64 + hi * 16);
      int kh = 30 * 32 + klane;
      short8 wf = *(const short8*)(smem + W1_OFF + (((lo * 2048 + 1024 + kh) * 2) ^ swz));
      l1a0 = MFMA(wf, a0, l1a0, 0,0,0); l1a1 = MFMA(wf, a1, l1a1, 0,0,0);
    }
    {
      WB0;
      const char* cb = chbase + (67 & 3) * 16384;
      short8 a0 = *(const short8*)(cb + lo * 64 + hi * 16);
      short8 a1 = *(const short8*)(cb + 1024 + lo * 64 + hi * 16);
      int kh = 31 * 32 + klane;
      short8 wf = *(const short8*)(smem + W1_OFF + (((lo * 2048 + 1024 + kh) * 2) ^ swz));
      l1a0 = MFMA(wf, a0, l1a0, 0,0,0); l1a1 = MFMA(wf, a1, l1a1, 0,0,0);
    }

    // epilogues: lane-local cell update (gates i,f,g,o in acc[0..3]); plain stores
    if (p < NSTEP) {
      unsigned short* ho = a.h0b + (size_t)wpar * NBATCH * NHID;
      float cn0 = sigf(l0a0[1] + b0r[1]) * c0r[0] + sigf(l0a0[0] + b0r[0]) * tanhf_(l0a0[2] + b0r[2]);
      c0r[0] = cn0;
      ho[(size_t)m0 * NHID + j] = f2bf(sigf(l0a0[3] + b0r[3]) * tanhf_(cn0));
      float cn1 = sigf(l0a1[1] + b0r[1]) * c0r[1] + sigf(l0a1[0] + b0r[0]) * tanhf_(l0a1[2] + b0r[2]);
      c0r[1] = cn1;
      ho[(size_t)m1 * NHID + j] = f2bf(sigf(l0a1[3] + b0r[3]) * tanhf_(cn1));
    }
    if (p >= 1) {
      unsigned short* h1o = a.h1b + (size_t)rp * NBATCH * NHID;
      unsigned short* oo  = a.outs + (size_t)(p - 1) * NBATCH * NHID;
      float cn0 = sigf(l1a0[1] + b1r[1]) * c1r[0] + sigf(l1a0[0] + b1r[0]) * tanhf_(l1a0[2] + b1r[2]);
      c1r[0] = cn0;
      unsigned short u0 = f2bf(sigf(l1a0[3] + b1r[3]) * tanhf_(cn0));
      h1o[(size_t)m0 * NHID + j] = u0; oo[(size_t)m0 * NHID + j] = u0;
      float cn1 = sigf(l1a1[1] + b1r[1]) * c1r[1] + sigf(l1a1[0] + b1r[0]) * tanhf_(l1a1[2] + b1r[2]);
      c1r[1] = cn1;
      unsigned short u1 = f2bf(sigf(l1a1[3] + b1r[3]) * tanhf_(cn1));
      h1o[(size_t)m1 * NHID + j] = u1; oo[(size_t)m1 * NHID + j] = u1;
    }
    slim_bar(a.ctr + p, tid);
  }

  cg::this_grid().sync();   // release outs + acquire for final GEMM

  // ---------------- final GEMM: out[i][o] = outs_flat[i,:] . Wout[o,:] + bout ----------------
  {
    int fnt = bx & 3, kc = bx >> 2;
    f32x4 facc[2][2];
    #pragma unroll
    for (int i = 0; i < 2; i++) { facc[i][0] = (f32x4)(0.f); facc[i][1] = (f32x4)(0.f); }
    const int kbase = kc * 2048;
    #pragma unroll 2
    for (int kk = 0; kk < 64; kk++) {
      short8 wf0 = ld8f(a.Wout + (size_t)(fnt * 32 +  0 + lo) * KOUT + kbase + kk * 32 + klane);
      short8 wf1 = ld8f(a.Wout + (size_t)(fnt * 32 + 16 + lo) * KOUT + kbase + kk * 32 + klane);
      #pragma unroll
      for (int mf = 0; mf < 2; mf++) {
        const unsigned short* ip = a.outs + (size_t)((w * 2 + mf) * 16 + lo) * KOUT + kbase + kk * 32 + klane;
        short8 af = ld8(ip);
        facc[mf][0] = MFMA(wf0, af, facc[mf][0], 0,0,0);
        facc[mf][1] = MFMA(wf1, af, facc[mf][1], 0,0,0);
      }
    }
    #pragma unroll
    for (int mf = 0; mf < 2; mf++)
      #pragma unroll
      for (int nf = 0; nf < 2; nf++)
        #pragma unroll
        for (int r = 0; r < 4; r++) {
          int o_loc = nf * 16 + 4 * hi + r;
          int i = (w * 2 + mf) * 16 + lo;
          a.partial[(size_t)(kc * 4 + fnt) * 8192 + o_loc * 256 + i] = facc[mf][nf][r];
        }
  }
  cg::this_grid().sync();

  for (int idx = gtid; idx < NBATCH * NOUT; idx += nthr) {
    int i = idx >> 7, o = idx & 127;
    float s = a.bout[o];
    #pragma unroll 4
    for (int kc2 = 0; kc2 < 64; kc2++)
      s += a.partial[(size_t)(kc2 * 4 + (o >> 5)) * 8192 + (o & 31) * 256 + i];
    a.out[idx] = s;
  }
}

extern "C" void kernel_launch(void* const* d_in, const int* in_sizes, int n_in,
                              void* d_out, int out_size, void* d_ws, size_t ws_size,
                              hipStream_t stream)
{
  (void)in_sizes; (void)n_in; (void)out_size; (void)ws_size;
  Params a;
  a.batch = (const float*)d_in[0];  a.Wih0 = (const float*)d_in[1];
  a.Whh0  = (const float*)d_in[2];  a.bih0 = (const float*)d_in[3];
  a.bhh0  = (const float*)d_in[4];  a.Wih1 = (const float*)d_in[5];
  a.Whh1  = (const float*)d_in[6];  a.bih1 = (const float*)d_in[7];
  a.bhh1  = (const float*)d_in[8];  a.h00  = (const float*)d_in[9];
  a.c00   = (const float*)d_in[10]; a.h01  = (const float*)d_in[11];
  a.c01   = (const float*)d_in[12]; a.Wout = (const float*)d_in[13];
  a.bout  = (const float*)d_in[14];
  a.out   = (float*)d_out;

  char* ws = (char*)d_ws;
  size_t off = 0;
  auto carve = [&](size_t bytes) { char* p = ws + off; off += (bytes + 255) & ~(size_t)255; return p; };
  a.h0b     = (unsigned short*)carve((size_t)2 * NBATCH * NHID * 2);
  a.h1b     = (unsigned short*)carve((size_t)2 * NBATCH * NHID * 2);
  a.outs    = (unsigned short*)carve((size_t)NSTEP * NBATCH * NHID * 2);
  a.xbf     = (unsigned short*)carve((size_t)NSTEP * NBATCH * NFEAT * 2);
  a.partial = (float*)carve((size_t)256 * 8192 * 4);
  a.ctr     = (unsigned*)carve((size_t)256 * 4);

  hipFuncSetAttribute((const void*)lstm_all, hipFuncAttributeMaxDynamicSharedMemorySize, SMEM_BYTES);

  void* kargs[] = { &a };
  hipLaunchCooperativeKernel((void*)lstm_all, dim3(256), dim3(512), kargs, SMEM_BYTES, stream);
}